// Round 11
// baseline (228.393 us; speedup 1.0000x reference)
//
#include <hip/hip_runtime.h>
#include <hip/hip_bf16.h>

typedef __bf16 bf16x8 __attribute__((ext_vector_type(8)));
typedef __bf16 bf16x4 __attribute__((ext_vector_type(4)));
typedef float  f32x4  __attribute__((ext_vector_type(4)));

#define H 768
#define LSEQ 2048
#define BATCH 32
#define MROWS (BATCH*LSEQ)   /* 65536 */
#define NT 6                 /* 768/128 n-tiles */
#define W2S 2304             /* W2 row stride (3H) */

__device__ __forceinline__ void gload_lds16(const void* g, void* l){
  __builtin_amdgcn_global_load_lds((const __attribute__((address_space(1))) void*)g,
                                   (__attribute__((address_space(3))) void*)l, 16, 0, 0);
}

// ---- convert W2c = W2[:, 2H:3H] to bf16 (row-major [g][h], h contiguous) ----
__global__ void w2c_cvt_k(const float* __restrict__ W2, __bf16* __restrict__ w2cb){
  int i4 = blockIdx.x*256 + threadIdx.x;     // 147456 float4s total
  int g  = i4 / 192;
  int hc = (i4 % 192) * 4;
  f32x4 v = *(const f32x4*)(W2 + (size_t)g*W2S + 1536 + hc);
  bf16x4 o; o[0]=(__bf16)v[0]; o[1]=(__bf16)v[1]; o[2]=(__bf16)v[2]; o[3]=(__bf16)v[3];
  *(bf16x4*)(w2cb + (size_t)g*H + hc) = o;
}

// ---- convert text (f32) -> bf16, 8 elems/thread, grid-stride ----
__global__ void text_cvt_k(const float* __restrict__ in, __bf16* __restrict__ outb){
  const size_t N8 = (size_t)MROWS*H/8;       // 6,291,456 groups of 8
  for (size_t i = blockIdx.x*256 + threadIdx.x; i < N8; i += (size_t)2048*256){
    f32x4 a = ((const f32x4*)in)[2*i], c = ((const f32x4*)in)[2*i+1];
    bf16x8 o;
    o[0]=(__bf16)a[0]; o[1]=(__bf16)a[1]; o[2]=(__bf16)a[2]; o[3]=(__bf16)a[3];
    o[4]=(__bf16)c[0]; o[5]=(__bf16)c[1]; o[6]=(__bf16)c[2]; o[7]=(__bf16)c[3];
    ((bf16x8*)outb)[i] = o;
  }
}

// ---- M = sum_g |W1[g]|  (logit bound: |h|<=1 after tanh) ----
__global__ void w1bound_k(const float* __restrict__ W1, float* __restrict__ Mout){
  int t = threadIdx.x;                       // 256 threads
  float s = fabsf(W1[t]) + fabsf(W1[t+256]) + fabsf(W1[t+512]);
  #pragma unroll
  for (int off=32; off>=1; off>>=1) s += __shfl_xor(s, off);
  __shared__ float sm[4];
  if ((t&63)==0) sm[t>>6] = s;
  __syncthreads();
  if (t==0) Mout[0] = sm[0]+sm[1]+sm[2]+sm[3];
}

// ---- bias_bh[b][g] = in1[b]·W2a[g] + in2[b]·W2b[g] + b2[g] ----
__global__ void bias_k(const float* __restrict__ in1, const float* __restrict__ in2,
                       const float* __restrict__ W2, const float* __restrict__ b2,
                       float* __restrict__ bias){
  int b = blockIdx.y;
  int g = blockIdx.x*64 + (threadIdx.x & 63);
  int q = threadIdx.x >> 6;                  // h-quarter
  const float* wa = W2 + (size_t)g*W2S + q*192;
  const float* wb = wa + H;
  const float* x1 = in1 + b*H + q*192;
  const float* x2 = in2 + b*H + q*192;
  float acc = 0.f;
  #pragma unroll 8
  for (int h=0; h<192; h+=4){
    f32x4 a4 = *(const f32x4*)(wa+h);
    f32x4 c4 = *(const f32x4*)(x1+h);
    f32x4 b4 = *(const f32x4*)(wb+h);
    f32x4 d4 = *(const f32x4*)(x2+h);
    acc += a4[0]*c4[0]+a4[1]*c4[1]+a4[2]*c4[2]+a4[3]*c4[3];
    acc += b4[0]*d4[0]+b4[1]*d4[1]+b4[2]*d4[2]+b4[3]*d4[3];
  }
  __shared__ float sm[4][64];
  sm[q][threadIdx.x&63] = acc;
  __syncthreads();
  if (q==0){
    float r = sm[0][threadIdx.x]+sm[1][threadIdx.x]+sm[2][threadIdx.x]+sm[3][threadIdx.x] + b2[g];
    bias[(size_t)b*H + g] = r;
  }
}

// ======================= fused GEMM: R9 structure + triple-buffer counted vmcnt ====
// Only change vs the verified R9 kernel: 3 LDS buffers, prefetch distance 2,
// per-step wait = vmcnt(4) (drains step kk+1's 4 gload_lds, leaves kk+2's 4 in
// flight) + raw s_barrier. No sched_barrier pinning (m141), no setprio (m190).
// All LDS reads & their lgkm waits are compiler-tracked (no rule-18 hazard);
// staging is gload_lds DMA only, so the manual vmcnt is the only needed wait.
__global__ __launch_bounds__(256,3) void fused_gemm_att_k(
    const __bf16* __restrict__ textb, const __bf16* __restrict__ w2cb,
    const float* __restrict__ bias, const float* __restrict__ W1,
    float* __restrict__ attp)
{
  __shared__ __align__(16) __bf16 a_lds[3][128*32];  // 24 KiB
  __shared__ __align__(16) __bf16 b_lds[3][128*32];  // 24 KiB
  __shared__ float att_lds[2][128];                  // 1 KiB

  int bid = blockIdx.x;                 // 3072 = 512 m-tiles * 6 n-tiles
  int lin = (bid & 7)*384 + (bid >> 3); // bijective XCD chunking (3072 % 8 == 0)
  int mt  = lin / 6;
  int nt  = lin % 6;
  int m0  = mt << 7;                    // 128 rows/tile
  int b   = mt >> 4;                    // 2048 rows/batch
  int t = threadIdx.x, lane = t & 63, wid = t >> 6;
  int wm = wid >> 1, wn = wid & 1;
  int fr = lane & 15, fc = lane >> 4;

  const __bf16* atile = textb + (size_t)m0*H;
  const __bf16* btile = w2cb + (size_t)(nt*128)*H;

  f32x4 acc[4][4];
  #pragma unroll
  for (int mi=0;mi<4;++mi)
    #pragma unroll
    for (int ni=0;ni<4;++ni) acc[mi][ni] = (f32x4){0.f,0.f,0.f,0.f};

  const __bf16 *asrc[2], *bsrc[2];
  int sdst[2];
  #pragma unroll
  for (int j=0;j<2;++j){
    int slot = wid*2 + j;
    int row = slot*16 + (lane>>2);
    int gs  = (lane&3) ^ ((row>>1)&3);
    asrc[j] = atile + (size_t)row*H + gs*8;
    bsrc[j] = btile + (size_t)row*H + gs*8;
    sdst[j] = slot*512 + lane*8;
  }
  int offA[4], offB[4];
  #pragma unroll
  for (int i=0;i<4;++i){
    int row = wm*64 + i*16 + fr;
    offA[i] = row*32 + ((fc ^ ((row>>1)&3))*8);
    int n = wn*64 + i*16 + fr;
    offB[i] = n*32 + ((fc ^ ((n>>1)&3))*8);
  }

  auto stage = [&](int bf, int kk){
    #pragma unroll
    for (int j=0;j<2;++j){
      gload_lds16(asrc[j] + kk*32, &a_lds[bf][sdst[j]]);
      gload_lds16(bsrc[j] + kk*32, &b_lds[bf][sdst[j]]);
    }
  };
  auto compute = [&](int bf){
    bf16x8 af[4], bq[4];
    #pragma unroll
    for (int i=0;i<4;++i){
      af[i] = *(const bf16x8*)&a_lds[bf][offA[i]];
      bq[i] = *(const bf16x8*)&b_lds[bf][offB[i]];
    }
    #pragma unroll
    for (int mi=0;mi<4;++mi)
      #pragma unroll
      for (int ni=0;ni<4;++ni)
        acc[mi][ni] = __builtin_amdgcn_mfma_f32_16x16x32_bf16(af[mi], bq[ni], acc[mi][ni], 0,0,0);
  };

  // prologue: stage steps 0 and 1; drain only step 0 (vmcnt(4)), leave 1 in flight
  stage(0, 0);
  stage(1, 1);
  asm volatile("s_waitcnt vmcnt(4)" ::: "memory");
  __builtin_amdgcn_s_barrier();

  // main loop: at step kk, issue stage(kk+2), compute(kk), then wait vmcnt(4)
  // (FIFO [S(kk+1):4][S(kk+2):4] -> drains S(kk+1)) + barrier.
  #pragma unroll 3
  for (int kk=0; kk<24; ++kk){
    if (kk+2 < 24) stage((kk+2)%3, kk+2);
    compute(kk%3);
    if (kk < 22){
      asm volatile("s_waitcnt vmcnt(4)" ::: "memory");
      __builtin_amdgcn_s_barrier();
    } else if (kk == 22){
      asm volatile("s_waitcnt vmcnt(0)" ::: "memory");
      __builtin_amdgcn_s_barrier();
    }
  }

  float bb[4], ww[4];
  int gb = nt*128 + wn*64 + fr;
  #pragma unroll
  for (int ni=0;ni<4;++ni){ bb[ni]=bias[(size_t)b*H + gb + ni*16]; ww[ni]=W1[gb + ni*16]; }

  float av[16];
  #pragma unroll
  for (int mi=0;mi<4;++mi)
    #pragma unroll
    for (int r=0;r<4;++r){
      float s = 0.f;
      #pragma unroll
      for (int ni=0;ni<4;++ni){
        float x = acc[mi][ni][r] + bb[ni];
        float e = __expf(2.0f*x);            // tanh(x) = (e^2x-1)/(e^2x+1)
        s += ww[ni] * ((e-1.0f)*__builtin_amdgcn_rcpf(e+1.0f));
      }
      av[mi*4+r] = s;
    }
  #pragma unroll
  for (int off=1; off<16; off<<=1)
    #pragma unroll
    for (int i=0;i<16;++i) av[i] += __shfl_xor(av[i], off);

  if (fr==0){
    #pragma unroll
    for (int mi=0;mi<4;++mi)
      #pragma unroll
      for (int r=0;r<4;++r)
        att_lds[wn][wm*64 + mi*16 + fc*4 + r] = av[mi*4+r];
  }
  __syncthreads();
  if (t < 128) attp[(size_t)nt*MROWS + m0 + t] = att_lds[0][t] + att_lds[1][t];
}

// ======================= FALLBACK fused (f32 text, from R9) =======================
__global__ __launch_bounds__(256,3) void fused_gemm_att_f32_k(
    const float* __restrict__ text, const __bf16* __restrict__ w2cb,
    const float* __restrict__ bias, const float* __restrict__ W1,
    float* __restrict__ attp)
{
  __shared__ __align__(16) __bf16 a_lds[2][128*32];
  __shared__ __align__(16) __bf16 b_lds[2][128*32];
  __shared__ float att_lds[2][128];

  int bid = blockIdx.x;
  int lin = (bid & 7)*384 + (bid >> 3);
  int mt  = lin / 6;
  int nt  = lin % 6;
  int m0  = mt << 7;
  int b   = mt >> 4;
  int t = threadIdx.x, lane = t & 63, wid = t >> 6;
  int wm = wid >> 1, wn = wid & 1;
  int fr = lane & 15, fc = lane >> 4;

  const float*  atile = text + (size_t)m0*H;
  const __bf16* btile = w2cb + (size_t)(nt*128)*H;

  f32x4 acc[4][4];
  #pragma unroll
  for (int mi=0;mi<4;++mi)
    #pragma unroll
    for (int ni=0;ni<4;++ni) acc[mi][ni] = (f32x4){0.f,0.f,0.f,0.f};

  int arow = t>>1, ahalf = t&1;
  const float* aptr = atile + (size_t)arow*H + ahalf*16;
  int awOff[2];
  #pragma unroll
  for (int j=0;j<2;++j) awOff[j] = arow*32 + ((2*ahalf + j) ^ ((arow>>1)&3))*8;
  f32x4 aReg[4];

  const __bf16* bsrc[2];
  int bdst[2];
  #pragma unroll
  for (int j=0;j<2;++j){
    int slot = wid*2 + j;
    int n = slot*16 + (lane>>2);
    bsrc[j] = btile + (size_t)n*H + ((lane&3)^((n>>1)&3))*8;
    bdst[j] = slot*512 + lane*8;
  }
  int offA[4], offB[4];
  #pragma unroll
  for (int i=0;i<4;++i){
    int row = wm*64 + i*16 + fr;
    offA[i] = row*32 + ((fc ^ ((row>>1)&3))*8);
    int n = wn*64 + i*16 + fr;
    offB[i] = n*32 + ((fc ^ ((n>>1)&3))*8);
  }
  auto loadA = [&](int kk){
    #pragma unroll
    for (int j=0;j<4;++j) aReg[j] = *(const f32x4*)(aptr + kk*32 + j*4);
  };
  auto writeA = [&](int bf){
    #pragma unroll
    for (int j=0;j<2;++j){
      bf16x8 v;
      v[0]=(__bf16)aReg[2*j][0]; v[1]=(__bf16)aReg[2*j][1];
      v[2]=(__bf16)aReg[2*j][2]; v[3]=(__bf16)aReg[2*j][3];
      v[4]=(__bf16)aReg[2*j+1][0]; v[5]=(__bf16)aReg[2*j+1][1];
      v[6]=(__bf16)aReg[2*j+1][2]; v[7]=(__bf16)aReg[2*j+1][3];
      *(bf16x8*)&a_lds[bf][awOff[j]] = v;
    }
  };
  auto stageB = [&](int bf, int kk){
    #pragma unroll
    for (int j=0;j<2;++j)
      gload_lds16(bsrc[j] + kk*32, &b_lds[bf][bdst[j]]);
  };
  auto compute = [&](int bf){
    bf16x8 af[4], bq[4];
    #pragma unroll
    for (int i=0;i<4;++i){
      af[i] = *(const bf16x8*)&a_lds[bf][offA[i]];
      bq[i] = *(const bf16x8*)&b_lds[bf][offB[i]];
    }
    #pragma unroll
    for (int mi=0;mi<4;++mi)
      #pragma unroll
      for (int ni=0;ni<4;++ni)
        acc[mi][ni] = __builtin_amdgcn_mfma_f32_16x16x32_bf16(af[mi], bq[ni], acc[mi][ni], 0,0,0);
  };

  loadA(0); writeA(0); stageB(0, 0); loadA(1);
  __syncthreads();
  #pragma unroll 2
  for (int kk=0; kk<24; ++kk){
    if (kk<23){ stageB((kk+1)&1, kk+1); writeA((kk+1)&1); if (kk<22) loadA(kk+2); }
    compute(kk&1);
    __syncthreads();
  }
  float bb[4], ww[4];
  int gb = nt*128 + wn*64 + fr;
  #pragma unroll
  for (int ni=0;ni<4;++ni){ bb[ni]=bias[(size_t)b*H + gb + ni*16]; ww[ni]=W1[gb + ni*16]; }
  float av[16];
  #pragma unroll
  for (int mi=0;mi<4;++mi)
    #pragma unroll
    for (int r=0;r<4;++r){
      float s = 0.f;
      #pragma unroll
      for (int ni=0;ni<4;++ni){
        float x = acc[mi][ni][r] + bb[ni];
        float e = __expf(2.0f*x);
        s += ww[ni] * ((e-1.0f)*__builtin_amdgcn_rcpf(e+1.0f));
      }
      av[mi*4+r] = s;
    }
  #pragma unroll
  for (int off=1; off<16; off<<=1)
    #pragma unroll
    for (int i=0;i<16;++i) av[i] += __shfl_xor(av[i], off);
  if (fr==0){
    #pragma unroll
    for (int mi=0;mi<4;++mi)
      #pragma unroll
      for (int r=0;r<4;++r)
        att_lds[wn][wm*64 + mi*16 + fc*4 + r] = av[mi*4+r];
  }
  __syncthreads();
  if (t < 128) attp[(size_t)nt*MROWS + m0 + t] = att_lds[0][t] + att_lds[1][t];
}

// ---- fused softmax-numerator + context partials (NO max pass: e = exp(v - M)) ----
template<bool BF16>
__global__ __launch_bounds__(192) void ctxatt_k(
    const void* __restrict__ textsrc, const float* __restrict__ attp,
    const float* __restrict__ tmask, const float* __restrict__ Mp,
    float* __restrict__ att_e, float* __restrict__ ctxp, float* __restrict__ esum)
{
  int chunk = blockIdx.x, b = blockIdx.y, t = threadIdx.x;
  size_t lbase = (size_t)b*LSEQ + chunk*64;
  __shared__ float se[64];
  float M = Mp[0];
  if (t < 64){
    size_t l = lbase + t;
    float v = 0.f;
    #pragma unroll
    for (int p=0;p<NT;++p) v += attp[(size_t)p*MROWS + l];
    v += (1.0f - tmask[l]) * -1.0e20f;
    float e = __expf(v - M);          // <= 1 by |tanh|<=1 bound; b1 cancels
    se[t] = e;
    att_e[l] = e;
    float s = e;
    #pragma unroll
    for (int off=32; off>=1; off>>=1) s += __shfl_xor(s, off);
    if (t==0) esum[b*32+chunk] = s;
  }
  __syncthreads();
  f32x4 acc = {0.f,0.f,0.f,0.f};
  if (BF16){
    const __bf16* tp = (const __bf16*)textsrc + lbase*H + 4*t;
    #pragma unroll 4
    for (int l=0;l<64;++l){
      float e = se[l];
      bf16x4 v = *(const bf16x4*)(tp + (size_t)l*H);
      acc[0] += e*(float)v[0]; acc[1] += e*(float)v[1];
      acc[2] += e*(float)v[2]; acc[3] += e*(float)v[3];
    }
  } else {
    const float* tp = (const float*)textsrc + lbase*H + 4*t;
    #pragma unroll 4
    for (int l=0;l<64;++l){
      float e = se[l];
      f32x4 v = *(const f32x4*)(tp + (size_t)l*H);
      acc[0] += e*v[0]; acc[1] += e*v[1]; acc[2] += e*v[2]; acc[3] += e*v[3];
    }
  }
  *(f32x4*)(ctxp + ((size_t)(b*32+chunk))*H + 4*t) = acc;
}

// ---- finalize: context = (sum ctxp)/sum_e ; att = e/sum_e ----
__global__ __launch_bounds__(768) void finctx_k(
    const float* __restrict__ ctxp, const float* __restrict__ esum,
    float* __restrict__ out, float* __restrict__ att_e)
{
  int b = blockIdx.x, t = threadIdx.x;   // 768 threads
  __shared__ float ss[32];
  if (t < 32) ss[t] = esum[b*32+t];
  __syncthreads();
  float s = 0.f;
  #pragma unroll
  for (int c=0;c<32;++c) s += ss[c];
  float inv = 1.0f/s;
  float cs = 0.f;
  #pragma unroll 8
  for (int c=0;c<32;++c) cs += ctxp[((size_t)(b*32+c))*H + t];
  out[(size_t)b*H + t] = cs * inv;
  for (int l=t; l<LSEQ; l+=768)
    att_e[(size_t)b*LSEQ + l] *= inv;
}

extern "C" void kernel_launch(void* const* d_in, const int* in_sizes, int n_in,
                              void* d_out, int out_size, void* d_ws, size_t ws_size,
                              hipStream_t stream){
  (void)in_sizes; (void)n_in; (void)out_size;
  const float* in1   = (const float*)d_in[0];
  const float* in2   = (const float*)d_in[1];
  const float* text  = (const float*)d_in[2];
  const float* tmask = (const float*)d_in[3];
  const float* W2    = (const float*)d_in[4];
  const float* b2    = (const float*)d_in[5];
  const float* W1    = (const float*)d_in[6];
  const float* b1    = (const float*)d_in[7];
  (void)b1;                                // cancels in softmax (shift invariance)
  float* out = (float*)d_out;              // [0,24576): context, [24576,90112): att
  char*  ws  = (char*)d_ws;
  // ws: w2cb 1179648 | biasb 98304 | attp 1572864 | ctxp 3145728 | esum 4096 | M 16 | textb 96MB
  __bf16* w2cb = (__bf16*)(ws);
  float* biasb = (float*)(ws + 1179648);
  float* attp  = (float*)(ws + 1277952);
  float* ctxp  = (float*)(ws + 2850816);
  float* esumb = (float*)(ws + 5996544);
  float* Mbuf  = (float*)(ws + 6000640);
  __bf16* textb = (__bf16*)(ws + 6000656);
  const size_t WS_NEEDED = 6000656ull + 100663296ull;
  float* att_out = out + BATCH*H;

  w2c_cvt_k <<<dim3(576),   dim3(256), 0, stream>>>(W2, w2cb);
  bias_k    <<<dim3(12,32), dim3(256), 0, stream>>>(in1, in2, W2, b2, biasb);
  w1bound_k <<<dim3(1),     dim3(256), 0, stream>>>(W1, Mbuf);
  if (ws_size >= WS_NEEDED){
    text_cvt_k      <<<dim3(2048), dim3(256), 0, stream>>>(text, textb);
    fused_gemm_att_k<<<dim3(3072), dim3(256), 0, stream>>>(textb, w2cb, biasb, W1, attp);
    ctxatt_k<true>  <<<dim3(32,32), dim3(192), 0, stream>>>(textb, attp, tmask, Mbuf, att_out, ctxp, esumb);
  } else {
    fused_gemm_att_f32_k<<<dim3(3072), dim3(256), 0, stream>>>(text, w2cb, biasb, W1, attp);
    ctxatt_k<false> <<<dim3(32,32), dim3(192), 0, stream>>>(text, attp, tmask, Mbuf, att_out, ctxp, esumb);
  }
  finctx_k  <<<dim3(32), dim3(768), 0, stream>>>(ctxp, esumb, out, att_out);
}

// Round 12
// 218.533 us; speedup vs baseline: 1.0451x; 1.0451x over previous
//
#include <hip/hip_runtime.h>
#include <hip/hip_bf16.h>

typedef __bf16 bf16x8 __attribute__((ext_vector_type(8)));
typedef __bf16 bf16x4 __attribute__((ext_vector_type(4)));
typedef float  f32x4  __attribute__((ext_vector_type(4)));

#define H 768
#define LSEQ 2048
#define BATCH 32
#define MROWS (BATCH*LSEQ)   /* 65536 */
#define NT 6                 /* 768/128 n-tiles */
#define W2S 2304             /* W2 row stride (3H) */

__device__ __forceinline__ void gload_lds16(const void* g, void* l){
  __builtin_amdgcn_global_load_lds((const __attribute__((address_space(1))) void*)g,
                                   (__attribute__((address_space(3))) void*)l, 16, 0, 0);
}

// ---- convert W2c = W2[:, 2H:3H] to bf16 (row-major [g][h], h contiguous) ----
__global__ void w2c_cvt_k(const float* __restrict__ W2, __bf16* __restrict__ w2cb){
  int i4 = blockIdx.x*256 + threadIdx.x;     // 147456 float4s total
  int g  = i4 / 192;
  int hc = (i4 % 192) * 4;
  f32x4 v = *(const f32x4*)(W2 + (size_t)g*W2S + 1536 + hc);
  bf16x4 o; o[0]=(__bf16)v[0]; o[1]=(__bf16)v[1]; o[2]=(__bf16)v[2]; o[3]=(__bf16)v[3];
  *(bf16x4*)(w2cb + (size_t)g*H + hc) = o;
}

// ---- convert text (f32) -> bf16, 8 elems/thread, grid-stride ----
__global__ void text_cvt_k(const float* __restrict__ in, __bf16* __restrict__ outb){
  const size_t N8 = (size_t)MROWS*H/8;       // 6,291,456 groups of 8
  for (size_t i = blockIdx.x*256 + threadIdx.x; i < N8; i += (size_t)2048*256){
    f32x4 a = ((const f32x4*)in)[2*i], c = ((const f32x4*)in)[2*i+1];
    bf16x8 o;
    o[0]=(__bf16)a[0]; o[1]=(__bf16)a[1]; o[2]=(__bf16)a[2]; o[3]=(__bf16)a[3];
    o[4]=(__bf16)c[0]; o[5]=(__bf16)c[1]; o[6]=(__bf16)c[2]; o[7]=(__bf16)c[3];
    ((bf16x8*)outb)[i] = o;
  }
}

// ---- M = sum_g |W1[g]|  (logit bound: |h|<=1 after tanh) ----
__global__ void w1bound_k(const float* __restrict__ W1, float* __restrict__ Mout){
  int t = threadIdx.x;                       // 256 threads
  float s = fabsf(W1[t]) + fabsf(W1[t+256]) + fabsf(W1[t+512]);
  #pragma unroll
  for (int off=32; off>=1; off>>=1) s += __shfl_xor(s, off);
  __shared__ float sm[4];
  if ((t&63)==0) sm[t>>6] = s;
  __syncthreads();
  if (t==0) Mout[0] = sm[0]+sm[1]+sm[2]+sm[3];
}

// ---- bias_bh[b][g] = in1[b]·W2a[g] + in2[b]·W2b[g] + b2[g] ----
// 4 batches per block (grid 12 x 8): W2 slice read ONCE per block instead of
// once per batch -> W2 traffic 302 MB -> ~10 MB; VALU-bound ~3-4 us.
__global__ void bias_k(const float* __restrict__ in1, const float* __restrict__ in2,
                       const float* __restrict__ W2, const float* __restrict__ b2,
                       float* __restrict__ bias){
  int bc = blockIdx.y;                       // 8 -> batches bc*4..bc*4+3
  int g  = blockIdx.x*64 + (threadIdx.x & 63);
  int q  = threadIdx.x >> 6;                 // h-quarter
  const float* wa = W2 + (size_t)g*W2S + q*192;
  const float* wb = wa + H;
  float acc[4] = {0.f,0.f,0.f,0.f};
  #pragma unroll 4
  for (int h=0; h<192; h+=4){
    f32x4 a4 = *(const f32x4*)(wa+h);
    f32x4 b4 = *(const f32x4*)(wb+h);
    #pragma unroll
    for (int j=0;j<4;++j){
      int b = bc*4 + j;
      f32x4 c4 = *(const f32x4*)(in1 + (size_t)b*H + q*192 + h);
      f32x4 d4 = *(const f32x4*)(in2 + (size_t)b*H + q*192 + h);
      acc[j] += a4[0]*c4[0]+a4[1]*c4[1]+a4[2]*c4[2]+a4[3]*c4[3]
              + b4[0]*d4[0]+b4[1]*d4[1]+b4[2]*d4[2]+b4[3]*d4[3];
    }
  }
  __shared__ float sm[4][64][4];
  #pragma unroll
  for (int j=0;j<4;++j) sm[q][threadIdx.x&63][j] = acc[j];
  __syncthreads();
  if (q==0){
    int gl = threadIdx.x;
    #pragma unroll
    for (int j=0;j<4;++j){
      float r = sm[0][gl][j]+sm[1][gl][j]+sm[2][gl][j]+sm[3][gl][j] + b2[g];
      bias[(size_t)(bc*4+j)*H + g] = r;
    }
  }
}

// ======================= fused GEMM (EXACT R9 revert -- verified best) =======================
__global__ __launch_bounds__(256,4) void fused_gemm_att_k(
    const __bf16* __restrict__ textb, const __bf16* __restrict__ w2cb,
    const float* __restrict__ bias, const float* __restrict__ W1,
    float* __restrict__ attp)
{
  __shared__ __align__(16) __bf16 a_lds[2][128*32];  // 16 KiB
  __shared__ __align__(16) __bf16 b_lds[2][128*32];  // 16 KiB
  __shared__ float att_lds[2][128];                  // 1 KiB

  int bid = blockIdx.x;                 // 3072 = 512 m-tiles * 6 n-tiles
  int lin = (bid & 7)*384 + (bid >> 3); // bijective XCD chunking (3072 % 8 == 0)
  int mt  = lin / 6;
  int nt  = lin % 6;
  int m0  = mt << 7;                    // 128 rows/tile
  int b   = mt >> 4;                    // 2048 rows/batch
  int t = threadIdx.x, lane = t & 63, wid = t >> 6;
  int wm = wid >> 1, wn = wid & 1;
  int fr = lane & 15, fc = lane >> 4;

  const __bf16* atile = textb + (size_t)m0*H;
  const __bf16* btile = w2cb + (size_t)(nt*128)*H;

  f32x4 acc[4][4];
  #pragma unroll
  for (int mi=0;mi<4;++mi)
    #pragma unroll
    for (int ni=0;ni<4;++ni) acc[mi][ni] = (f32x4){0.f,0.f,0.f,0.f};

  const __bf16 *asrc[2], *bsrc[2];
  int sdst[2];
  #pragma unroll
  for (int j=0;j<2;++j){
    int slot = wid*2 + j;
    int row = slot*16 + (lane>>2);
    int gs  = (lane&3) ^ ((row>>1)&3);
    asrc[j] = atile + (size_t)row*H + gs*8;
    bsrc[j] = btile + (size_t)row*H + gs*8;
    sdst[j] = slot*512 + lane*8;
  }
  int offA[4], offB[4];
  #pragma unroll
  for (int i=0;i<4;++i){
    int row = wm*64 + i*16 + fr;
    offA[i] = row*32 + ((fc ^ ((row>>1)&3))*8);
    int n = wn*64 + i*16 + fr;
    offB[i] = n*32 + ((fc ^ ((n>>1)&3))*8);
  }

  auto stage = [&](int bf, int kk){
    #pragma unroll
    for (int j=0;j<2;++j){
      gload_lds16(asrc[j] + kk*32, &a_lds[bf][sdst[j]]);
      gload_lds16(bsrc[j] + kk*32, &b_lds[bf][sdst[j]]);
    }
  };
  auto compute = [&](int bf){
    bf16x8 af[4], bq[4];
    #pragma unroll
    for (int i=0;i<4;++i){
      af[i] = *(const bf16x8*)&a_lds[bf][offA[i]];
      bq[i] = *(const bf16x8*)&b_lds[bf][offB[i]];
    }
    #pragma unroll
    for (int mi=0;mi<4;++mi)
      #pragma unroll
      for (int ni=0;ni<4;++ni)
        acc[mi][ni] = __builtin_amdgcn_mfma_f32_16x16x32_bf16(af[mi], bq[ni], acc[mi][ni], 0,0,0);
  };

  stage(0, 0);
  __syncthreads();
  #pragma unroll 2
  for (int kk=0; kk<24; ++kk){
    if (kk < 23) stage((kk+1)&1, kk+1);
    compute(kk&1);
    __syncthreads();
  }

  float bb[4], ww[4];
  int gb = nt*128 + wn*64 + fr;
  #pragma unroll
  for (int ni=0;ni<4;++ni){ bb[ni]=bias[(size_t)b*H + gb + ni*16]; ww[ni]=W1[gb + ni*16]; }

  float av[16];
  #pragma unroll
  for (int mi=0;mi<4;++mi)
    #pragma unroll
    for (int r=0;r<4;++r){
      float s = 0.f;
      #pragma unroll
      for (int ni=0;ni<4;++ni){
        float x = acc[mi][ni][r] + bb[ni];
        float e = __expf(2.0f*x);            // tanh(x) = (e^2x-1)/(e^2x+1)
        s += ww[ni] * ((e-1.0f)*__builtin_amdgcn_rcpf(e+1.0f));
      }
      av[mi*4+r] = s;
    }
  #pragma unroll
  for (int off=1; off<16; off<<=1)
    #pragma unroll
    for (int i=0;i<16;++i) av[i] += __shfl_xor(av[i], off);

  if (fr==0){
    #pragma unroll
    for (int mi=0;mi<4;++mi)
      #pragma unroll
      for (int r=0;r<4;++r)
        att_lds[wn][wm*64 + mi*16 + fc*4 + r] = av[mi*4+r];
  }
  __syncthreads();
  if (t < 128) attp[(size_t)nt*MROWS + m0 + t] = att_lds[0][t] + att_lds[1][t];
}

// ======================= FALLBACK fused (f32 text) =======================
__global__ __launch_bounds__(256,3) void fused_gemm_att_f32_k(
    const float* __restrict__ text, const __bf16* __restrict__ w2cb,
    const float* __restrict__ bias, const float* __restrict__ W1,
    float* __restrict__ attp)
{
  __shared__ __align__(16) __bf16 a_lds[2][128*32];
  __shared__ __align__(16) __bf16 b_lds[2][128*32];
  __shared__ float att_lds[2][128];

  int bid = blockIdx.x;
  int lin = (bid & 7)*384 + (bid >> 3);
  int mt  = lin / 6;
  int nt  = lin % 6;
  int m0  = mt << 7;
  int b   = mt >> 4;
  int t = threadIdx.x, lane = t & 63, wid = t >> 6;
  int wm = wid >> 1, wn = wid & 1;
  int fr = lane & 15, fc = lane >> 4;

  const float*  atile = text + (size_t)m0*H;
  const __bf16* btile = w2cb + (size_t)(nt*128)*H;

  f32x4 acc[4][4];
  #pragma unroll
  for (int mi=0;mi<4;++mi)
    #pragma unroll
    for (int ni=0;ni<4;++ni) acc[mi][ni] = (f32x4){0.f,0.f,0.f,0.f};

  int arow = t>>1, ahalf = t&1;
  const float* aptr = atile + (size_t)arow*H + ahalf*16;
  int awOff[2];
  #pragma unroll
  for (int j=0;j<2;++j) awOff[j] = arow*32 + ((2*ahalf + j) ^ ((arow>>1)&3))*8;
  f32x4 aReg[4];

  const __bf16* bsrc[2];
  int bdst[2];
  #pragma unroll
  for (int j=0;j<2;++j){
    int slot = wid*2 + j;
    int n = slot*16 + (lane>>2);
    bsrc[j] = btile + (size_t)n*H + ((lane&3)^((n>>1)&3))*8;
    bdst[j] = slot*512 + lane*8;
  }
  int offA[4], offB[4];
  #pragma unroll
  for (int i=0;i<4;++i){
    int row = wm*64 + i*16 + fr;
    offA[i] = row*32 + ((fc ^ ((row>>1)&3))*8);
    int n = wn*64 + i*16 + fr;
    offB[i] = n*32 + ((fc ^ ((n>>1)&3))*8);
  }
  auto loadA = [&](int kk){
    #pragma unroll
    for (int j=0;j<4;++j) aReg[j] = *(const f32x4*)(aptr + kk*32 + j*4);
  };
  auto writeA = [&](int bf){
    #pragma unroll
    for (int j=0;j<2;++j){
      bf16x8 v;
      v[0]=(__bf16)aReg[2*j][0]; v[1]=(__bf16)aReg[2*j][1];
      v[2]=(__bf16)aReg[2*j][2]; v[3]=(__bf16)aReg[2*j][3];
      v[4]=(__bf16)aReg[2*j+1][0]; v[5]=(__bf16)aReg[2*j+1][1];
      v[6]=(__bf16)aReg[2*j+1][2]; v[7]=(__bf16)aReg[2*j+1][3];
      *(bf16x8*)&a_lds[bf][awOff[j]] = v;
    }
  };
  auto stageB = [&](int bf, int kk){
    #pragma unroll
    for (int j=0;j<2;++j)
      gload_lds16(bsrc[j] + kk*32, &b_lds[bf][bdst[j]]);
  };
  auto compute = [&](int bf){
    bf16x8 af[4], bq[4];
    #pragma unroll
    for (int i=0;i<4;++i){
      af[i] = *(const bf16x8*)&a_lds[bf][offA[i]];
      bq[i] = *(const bf16x8*)&b_lds[bf][offB[i]];
    }
    #pragma unroll
    for (int mi=0;mi<4;++mi)
      #pragma unroll
      for (int ni=0;ni<4;++ni)
        acc[mi][ni] = __builtin_amdgcn_mfma_f32_16x16x32_bf16(af[mi], bq[ni], acc[mi][ni], 0,0,0);
  };

  loadA(0); writeA(0); stageB(0, 0); loadA(1);
  __syncthreads();
  #pragma unroll 2
  for (int kk=0; kk<24; ++kk){
    if (kk<23){ stageB((kk+1)&1, kk+1); writeA((kk+1)&1); if (kk<22) loadA(kk+2); }
    compute(kk&1);
    __syncthreads();
  }
  float bb[4], ww[4];
  int gb = nt*128 + wn*64 + fr;
  #pragma unroll
  for (int ni=0;ni<4;++ni){ bb[ni]=bias[(size_t)b*H + gb + ni*16]; ww[ni]=W1[gb + ni*16]; }
  float av[16];
  #pragma unroll
  for (int mi=0;mi<4;++mi)
    #pragma unroll
    for (int r=0;r<4;++r){
      float s = 0.f;
      #pragma unroll
      for (int ni=0;ni<4;++ni){
        float x = acc[mi][ni][r] + bb[ni];
        float e = __expf(2.0f*x);
        s += ww[ni] * ((e-1.0f)*__builtin_amdgcn_rcpf(e+1.0f));
      }
      av[mi*4+r] = s;
    }
  #pragma unroll
  for (int off=1; off<16; off<<=1)
    #pragma unroll
    for (int i=0;i<16;++i) av[i] += __shfl_xor(av[i], off);
  if (fr==0){
    #pragma unroll
    for (int mi=0;mi<4;++mi)
      #pragma unroll
      for (int r=0;r<4;++r)
        att_lds[wn][wm*64 + mi*16 + fc*4 + r] = av[mi*4+r];
  }
  __syncthreads();
  if (t < 128) attp[(size_t)nt*MROWS + m0 + t] = att_lds[0][t] + att_lds[1][t];
}

// ---- fused softmax-numerator + context partials (NO max pass: e = exp(v - M)) ----
template<bool BF16>
__global__ __launch_bounds__(192) void ctxatt_k(
    const void* __restrict__ textsrc, const float* __restrict__ attp,
    const float* __restrict__ tmask, const float* __restrict__ Mp,
    float* __restrict__ att_e, float* __restrict__ ctxp, float* __restrict__ esum)
{
  int chunk = blockIdx.x, b = blockIdx.y, t = threadIdx.x;
  size_t lbase = (size_t)b*LSEQ + chunk*64;
  __shared__ float se[64];
  float M = Mp[0];
  if (t < 64){
    size_t l = lbase + t;
    float v = 0.f;
    #pragma unroll
    for (int p=0;p<NT;++p) v += attp[(size_t)p*MROWS + l];
    v += (1.0f - tmask[l]) * -1.0e20f;
    float e = __expf(v - M);          // <= 1 by |tanh|<=1 bound; b1 cancels
    se[t] = e;
    att_e[l] = e;
    float s = e;
    #pragma unroll
    for (int off=32; off>=1; off>>=1) s += __shfl_xor(s, off);
    if (t==0) esum[b*32+chunk] = s;
  }
  __syncthreads();
  f32x4 acc = {0.f,0.f,0.f,0.f};
  if (BF16){
    const __bf16* tp = (const __bf16*)textsrc + lbase*H + 4*t;
    #pragma unroll 4
    for (int l=0;l<64;++l){
      float e = se[l];
      bf16x4 v = *(const bf16x4*)(tp + (size_t)l*H);
      acc[0] += e*(float)v[0]; acc[1] += e*(float)v[1];
      acc[2] += e*(float)v[2]; acc[3] += e*(float)v[3];
    }
  } else {
    const float* tp = (const float*)textsrc + lbase*H + 4*t;
    #pragma unroll 4
    for (int l=0;l<64;++l){
      float e = se[l];
      f32x4 v = *(const f32x4*)(tp + (size_t)l*H);
      acc[0] += e*v[0]; acc[1] += e*v[1]; acc[2] += e*v[2]; acc[3] += e*v[3];
    }
  }
  *(f32x4*)(ctxp + ((size_t)(b*32+chunk))*H + 4*t) = acc;
}

// ---- finalize: context = (sum ctxp)/sum_e ; att = e/sum_e ----
__global__ __launch_bounds__(768) void finctx_k(
    const float* __restrict__ ctxp, const float* __restrict__ esum,
    float* __restrict__ out, float* __restrict__ att_e)
{
  int b = blockIdx.x, t = threadIdx.x;   // 768 threads
  __shared__ float ss[32];
  if (t < 32) ss[t] = esum[b*32+t];
  __syncthreads();
  float s = 0.f;
  #pragma unroll
  for (int c=0;c<32;++c) s += ss[c];
  float inv = 1.0f/s;
  float cs = 0.f;
  #pragma unroll 8
  for (int c=0;c<32;++c) cs += ctxp[((size_t)(b*32+c))*H + t];
  out[(size_t)b*H + t] = cs * inv;
  for (int l=t; l<LSEQ; l+=768)
    att_e[(size_t)b*LSEQ + l] *= inv;
}

extern "C" void kernel_launch(void* const* d_in, const int* in_sizes, int n_in,
                              void* d_out, int out_size, void* d_ws, size_t ws_size,
                              hipStream_t stream){
  (void)in_sizes; (void)n_in; (void)out_size;
  const float* in1   = (const float*)d_in[0];
  const float* in2   = (const float*)d_in[1];
  const float* text  = (const float*)d_in[2];
  const float* tmask = (const float*)d_in[3];
  const float* W2    = (const float*)d_in[4];
  const float* b2    = (const float*)d_in[5];
  const float* W1    = (const float*)d_in[6];
  const float* b1    = (const float*)d_in[7];
  (void)b1;                                // cancels in softmax (shift invariance)
  float* out = (float*)d_out;              // [0,24576): context, [24576,90112): att
  char*  ws  = (char*)d_ws;
  // ws: w2cb 1179648 | biasb 98304 | attp 1572864 | ctxp 3145728 | esum 4096 | M 16 | textb 96MB
  __bf16* w2cb = (__bf16*)(ws);
  float* biasb = (float*)(ws + 1179648);
  float* attp  = (float*)(ws + 1277952);
  float* ctxp  = (float*)(ws + 2850816);
  float* esumb = (float*)(ws + 5996544);
  float* Mbuf  = (float*)(ws + 6000640);
  __bf16* textb = (__bf16*)(ws + 6000656);
  const size_t WS_NEEDED = 6000656ull + 100663296ull;
  float* att_out = out + BATCH*H;

  w2c_cvt_k <<<dim3(576),   dim3(256), 0, stream>>>(W2, w2cb);
  bias_k    <<<dim3(12,8),  dim3(256), 0, stream>>>(in1, in2, W2, b2, biasb);
  w1bound_k <<<dim3(1),     dim3(256), 0, stream>>>(W1, Mbuf);
  if (ws_size >= WS_NEEDED){
    text_cvt_k      <<<dim3(2048), dim3(256), 0, stream>>>(text, textb);
    fused_gemm_att_k<<<dim3(3072), dim3(256), 0, stream>>>(textb, w2cb, biasb, W1, attp);
    ctxatt_k<true>  <<<dim3(32,32), dim3(192), 0, stream>>>(textb, attp, tmask, Mbuf, att_out, ctxp, esumb);
  } else {
    fused_gemm_att_f32_k<<<dim3(3072), dim3(256), 0, stream>>>(text, w2cb, biasb, W1, attp);
    ctxatt_k<false> <<<dim3(32,32), dim3(192), 0, stream>>>(text, attp, tmask, Mbuf, att_out, ctxp, esumb);
  }
  finctx_k  <<<dim3(32), dim3(768), 0, stream>>>(ctxp, esumb, out, att_out);
}